// Round 12
// baseline (102.275 us; speedup 1.0000x reference)
//
#include <hip/hip_runtime.h>

typedef _Float16 f16x8 __attribute__((ext_vector_type(8)));
typedef float f32x16 __attribute__((ext_vector_type(16)));

#define TRUNC_VAL 2.0f
#define NBINS 4096     // 16^3 Morton bins
#define GRID_LO  -4.0f
#define GRID_INV  2.0f
#define CW 8           // chamfer waves per block

// ---------------------------------------------------------------------------
// R12: exact pruning (R10/R11, absmax 0.0) with two fixes:
//  1. chamfer phase 2 = best-first: each wave extracts its min-LB tile and
//     RE-TIGHTENS its ub after every tile (wave-local partial-min bound is
//     a valid skip threshold; min(block_ub, wave_ub) preserves exactness).
//     R11's stale block-wide ub left fringe waves sweeping dozens of tiles.
//  2. prep 6 -> 4 dispatches: binscan fuses code+hist+scan in LDS (memset
//     and the global-atomic hist pass deleted); scatter gets rank from
//     atomicAdd on the scanned hist.
// No device-scope fences (R2). ILP-2 dense phase (R8 recipe).
// ---------------------------------------------------------------------------

__device__ __forceinline__ unsigned mort4(unsigned v) {
    return (v & 1u) | ((v & 2u) << 2) | ((v & 4u) << 4) | ((v & 8u) << 6);
}

// set: 0 = p1 (fw targets), 1 = p0 (bw targets), 2 = p0+fw (fw queries),
//      3 = p0+fw-bw (bw queries)
__device__ __forceinline__ void load_point(int set, int i,
        const float* __restrict__ fw, const float* __restrict__ bw,
        const float* __restrict__ p0, const float* __restrict__ p1,
        float& x, float& y, float& z) {
    if (set == 0) { x = p1[3*i]; y = p1[3*i+1]; z = p1[3*i+2]; }
    else {
        x = p0[3*i]; y = p0[3*i+1]; z = p0[3*i+2];
        if (set >= 2) { x += fw[3*i]; y += fw[3*i+1]; z += fw[3*i+2]; }
        if (set == 3) { x -= bw[3*i]; y -= bw[3*i+1]; z -= bw[3*i+2]; }
    }
}

// --- P1: per-set fused code + LDS histogram + LDS scan (1 block per set) --
__global__ __launch_bounds__(1024) void binscan_kernel(
        const float* __restrict__ fw, const float* __restrict__ bw,
        const float* __restrict__ p0, const float* __restrict__ p1,
        int* __restrict__ hist, unsigned short* __restrict__ aux,
        float* __restrict__ out, int N) {
    __shared__ int h[NBINS];
    __shared__ int tmp[1024];
    int set = blockIdx.x;
    int tid = threadIdx.x;
    if (set == 0 && tid == 0) out[0] = 0.0f;
    #pragma unroll
    for (int k = 0; k < NBINS / 1024; ++k) h[tid + k * 1024] = 0;
    __syncthreads();
    for (int k = 0; k < N / 1024; ++k) {
        int i = tid + k * 1024;
        float x, y, z; load_point(set, i, fw, bw, p0, p1, x, y, z);
        int xi = (int)((x - GRID_LO) * GRID_INV); xi = xi < 0 ? 0 : (xi > 15 ? 15 : xi);
        int yi = (int)((y - GRID_LO) * GRID_INV); yi = yi < 0 ? 0 : (yi > 15 ? 15 : yi);
        int zi = (int)((z - GRID_LO) * GRID_INV); zi = zi < 0 ? 0 : (zi > 15 ? 15 : zi);
        unsigned code = mort4(xi) | (mort4(yi) << 1) | (mort4(zi) << 2);
        aux[(size_t)set * N + i] = (unsigned short)code;
        atomicAdd(&h[code], 1);
    }
    __syncthreads();
    int v[NBINS / 1024], s = 0;
    #pragma unroll
    for (int k = 0; k < NBINS / 1024; ++k) { v[k] = h[tid * (NBINS/1024) + k]; s += v[k]; }
    tmp[tid] = s; __syncthreads();
    for (int off = 1; off < 1024; off <<= 1) {
        int x = (tid >= off) ? tmp[tid - off] : 0;
        __syncthreads();
        tmp[tid] += x;
        __syncthreads();
    }
    int excl = tmp[tid] - s;
    #pragma unroll
    for (int k = 0; k < NBINS / 1024; ++k) {
        hist[set * NBINS + tid * (NBINS/1024) + k] = excl; excl += v[k];
    }
}

// --- P2: scatter (rank via atomicAdd on the scanned hist) -----------------
__global__ void scatter_kernel(const float* __restrict__ fw, const float* __restrict__ bw,
                               const float* __restrict__ p0, const float* __restrict__ p1,
                               int* __restrict__ hist, const unsigned short* __restrict__ aux,
                               float4* __restrict__ S, int N) {
    int i = blockIdx.x * blockDim.x + threadIdx.x;
    int set = blockIdx.z;
    if (i >= N) return;
    unsigned code = aux[(size_t)set * N + i];
    int pos = atomicAdd(&hist[set * NBINS + (int)code], 1);
    float x, y, z; load_point(set, i, fw, bw, p0, p1, x, y, z);
    S[(size_t)set * N + pos] = make_float4(x, y, z, x*x + y*y + z*z);
}

// --- P3: A-panels (MFMA frags) + tile bounding boxes ----------------------
__global__ __launch_bounds__(256) void panel_kernel(const float4* __restrict__ S,
        f16x8* __restrict__ Apanel, float4* __restrict__ TLo, float4* __restrict__ THi,
        int N, int nt) {
    int z = blockIdx.z;
    int tile = blockIdx.x * 4 + (threadIdx.x >> 6);
    int lane = threadIdx.x & 63, r = lane & 31;
    bool hi = lane >= 32;
    float4 pt = S[(size_t)z * N + tile * 32 + r];
    float x = pt.x, y = pt.y, zc = pt.z;
    _Float16 xh = (_Float16)x, yh = (_Float16)y, zh = (_Float16)zc;
    _Float16 xl = (_Float16)(x  - (float)xh);
    _Float16 yl = (_Float16)(y  - (float)yh);
    _Float16 zl = (_Float16)(zc - (float)zh);
    float w = -0.5f * pt.w;
    _Float16 wh = (_Float16)w, wl = (_Float16)(w - (float)wh);
    f16x8 o;
    if (!hi) { o[0]=xh; o[1]=yh; o[2]=zh; o[3]=xh; o[4]=yh; o[5]=zh; o[6]=xl; o[7]=yl; }
    else {
        o[0]=zl; o[1]=wh; o[2]=wl;
        o[3]=(_Float16)0.0f; o[4]=(_Float16)0.0f; o[5]=(_Float16)0.0f;
        o[6]=(_Float16)0.0f; o[7]=(_Float16)0.0f;
    }
    Apanel[(size_t)z * nt * 64 + tile * 64 + lane] = o;
    float lx=x, ly=y, lz=zc, hx=x, hy=y, hz=zc;
    #pragma unroll
    for (int off = 1; off < 64; off <<= 1) {
        lx = fminf(lx, __shfl_xor(lx, off, 64));
        ly = fminf(ly, __shfl_xor(ly, off, 64));
        lz = fminf(lz, __shfl_xor(lz, off, 64));
        hx = fmaxf(hx, __shfl_xor(hx, off, 64));
        hy = fmaxf(hy, __shfl_xor(hy, off, 64));
        hz = fmaxf(hz, __shfl_xor(hz, off, 64));
    }
    if (lane == 0) {
        TLo[z * nt + tile] = make_float4(lx, ly, lz, 0.0f);
        THi[z * nt + tile] = make_float4(hx, hy, hz, 0.0f);
    }
}

#define FOLD(d)                                                     \
    _Pragma("unroll")                                               \
    for (int p = 0; p < 4; ++p) {                                   \
        m[p] = fmaxf(fmaxf(m[p], d[4*p  ]), d[4*p+1]);              \
        m[p] = fmaxf(fmaxf(m[p], d[4*p+2]), d[4*p+3]);              \
    }

// --- C: pruned chamfer, best-first phase 2. One block = (query tile, dir).-
__global__ __launch_bounds__(64 * CW, 4) void chamfer_fused(
        const f16x8* __restrict__ Apanel, const float4* __restrict__ S,
        const float4* __restrict__ TLo, const float4* __restrict__ THi,
        float* __restrict__ out, int N, float inv, int nt) {
    __shared__ float sM[CW][32];
    int tid = threadIdx.x;
    int lane = tid & 63, w = tid >> 6;
    int qt = blockIdx.x, z = blockIdx.z;
    int r = lane & 31; bool hi = lane >= 32;
    const f16x8* Ap = Apanel + (size_t)z * nt * 64;

    float4 q4 = S[(size_t)(2 + z) * N + qt * 32 + r];

    // B fragment (identical layout to the verified pack)
    float qx = q4.x, qy = q4.y, qz = q4.z;
    _Float16 xh = (_Float16)qx, yh = (_Float16)qy, zh = (_Float16)qz;
    _Float16 xl = (_Float16)(qx - (float)xh);
    _Float16 yl = (_Float16)(qy - (float)yh);
    _Float16 zl = (_Float16)(qz - (float)zh);
    f16x8 b;
    if (!hi) { b[0]=xh; b[1]=yh; b[2]=zh; b[3]=xl; b[4]=yl; b[5]=zl; b[6]=xh; b[7]=yh; }
    else {
        b[0]=zh; b[1]=(_Float16)1.0f; b[2]=(_Float16)1.0f;
        b[3]=(_Float16)0.0f; b[4]=(_Float16)0.0f; b[5]=(_Float16)0.0f;
        b[6]=(_Float16)0.0f; b[7]=(_Float16)0.0f;
    }

    // query-tile bounding box
    float qlx=qx, qly=qy, qlz=qz, qhx=qx, qhy=qy, qhz=qz;
    #pragma unroll
    for (int off = 1; off < 64; off <<= 1) {
        qlx = fminf(qlx, __shfl_xor(qlx, off, 64));
        qly = fminf(qly, __shfl_xor(qly, off, 64));
        qlz = fminf(qlz, __shfl_xor(qlz, off, 64));
        qhx = fmaxf(qhx, __shfl_xor(qhx, off, 64));
        qhy = fmaxf(qhy, __shfl_xor(qhy, off, 64));
        qhz = fmaxf(qhz, __shfl_xor(qhz, off, 64));
    }

    // lane owns tile (w + 8g)*16 + (lane&15), g = lane>>4
    int g = lane >> 4;
    int myTile = (w + CW * g) * 16 + (lane & 15);
    float4 lo = TLo[z * nt + myTile], hb = THi[z * nt + myTile];
    float gx = fmaxf(0.0f, fmaxf(lo.x - qhx, qlx - hb.x));
    float gy = fmaxf(0.0f, fmaxf(lo.y - qhy, qly - hb.y));
    float gz = fmaxf(0.0f, fmaxf(lo.z - qhz, qlz - hb.z));
    float lb = gx*gx + gy*gy + gz*gz;

    // wave-local nearest segment (min LB within each 16-lane group)
    float slb = lb;
    #pragma unroll
    for (int off = 1; off < 16; off <<= 1) slb = fminf(slb, __shfl_xor(slb, off, 64));
    float s0v = slb; int s0g = g;
    #pragma unroll
    for (int off = 16; off < 64; off <<= 1) {
        float ov = __shfl_xor(s0v, off, 64);
        int   og = __shfl_xor(s0g, off, 64);
        if (ov < s0v || (ov == s0v && og < s0g)) { s0v = ov; s0g = og; }
    }

    float m[4] = { -3.0e38f, -3.0e38f, -3.0e38f, -3.0e38f };
    const f32x16 zero = {};

    // ---- phase 1: dense ILP-2 sweep of the wave's nearest segment ----
    int tb0 = (w + CW * s0g) * 16;
    f16x8 a0 = Ap[(size_t)(tb0    ) * 64 + lane];
    f16x8 a1 = Ap[(size_t)(tb0 + 1) * 64 + lane];
    for (int t = 0; t < 16; t += 2) {
        f16x8 c0 = a0, c1 = a1;
        int t2 = (t + 2 < 16) ? t + 2 : t;
        int t3 = (t + 3 < 16) ? t + 3 : t + 1;
        a0 = Ap[(size_t)(tb0 + t2) * 64 + lane];
        a1 = Ap[(size_t)(tb0 + t3) * 64 + lane];
        f32x16 d0 = __builtin_amdgcn_mfma_f32_32x32x16_f16(c0, b, zero, 0, 0, 0);
        f32x16 d1 = __builtin_amdgcn_mfma_f32_32x32x16_f16(c1, b, zero, 0, 0, 0);
        FOLD(d0) FOLD(d1)
    }
    if (g == s0g) lb = 3.0e38f;               // mark phase-1 tiles processed

    // ---- block-wide ub from all 8 waves' phase-1 results ----
    float v = fmaxf(fmaxf(m[0], m[1]), fmaxf(m[2], m[3]));
    v = fmaxf(v, __shfl_xor(v, 32, 64));
    if (lane < 32) sM[w][lane] = v;
    __syncthreads();
    float mx = sM[0][r];
    #pragma unroll
    for (int ww = 1; ww < CW; ++ww) mx = fmaxf(mx, sM[ww][r]);
    float d2c = fmaf(-2.0f, mx, q4.w);
    d2c = fmaxf(d2c, 0.0f); d2c = fminf(d2c, TRUNC_VAL);
    float ub = d2c;
    #pragma unroll
    for (int off = 1; off < 64; off <<= 1) ub = fmaxf(ub, __shfl_xor(ub, off, 64));
    __syncthreads();                          // sM free for reuse

    // ---- phase 2: best-first — extract min-LB tile, process, tighten ub --
    for (int it = 0; it < 48; ++it) {
        float mv = lb; int mi = myTile;
        #pragma unroll
        for (int off = 1; off < 64; off <<= 1) {
            float ov = __shfl_xor(mv, off, 64);
            int   oi = __shfl_xor(mi, off, 64);
            if (ov < mv || (ov == mv && oi < mi)) { mv = ov; mi = oi; }
        }
        if (mv >= ub) break;
        f16x8 a = Ap[(size_t)mi * 64 + lane];
        f32x16 d = __builtin_amdgcn_mfma_f32_32x32x16_f16(a, b, zero, 0, 0, 0);
        FOLD(d)
        if (myTile == mi) lb = 3.0e38f;
        // wave-local ub refinement (valid: partial min >= final min)
        float vv = fmaxf(fmaxf(m[0], m[1]), fmaxf(m[2], m[3]));
        vv = fmaxf(vv, __shfl_xor(vv, 32, 64));
        float dd = fmaf(-2.0f, vv, q4.w);
        dd = fmaxf(dd, 0.0f); dd = fminf(dd, TRUNC_VAL);
        #pragma unroll
        for (int off = 1; off < 64; off <<= 1) dd = fmaxf(dd, __shfl_xor(dd, off, 64));
        ub = fminf(ub, dd);
    }

    // ---- final combine, truncated chamfer, block sum, one atomicAdd ----
    v = fmaxf(fmaxf(m[0], m[1]), fmaxf(m[2], m[3]));
    v = fmaxf(v, __shfl_xor(v, 32, 64));
    if (lane < 32) sM[w][lane] = v;
    __syncthreads();
    if (w == 0) {
        float mx2 = sM[0][r];
        #pragma unroll
        for (int ww = 1; ww < CW; ++ww) mx2 = fmaxf(mx2, sM[ww][r]);
        float d2 = fmaf(-2.0f, mx2, q4.w);
        d2 = fmaxf(d2, 0.0f);
        float dc = fminf(d2, TRUNC_VAL);
        float c = (lane < 32) ? dc : 0.0f;
        #pragma unroll
        for (int off = 1; off < 64; off <<= 1) c += __shfl_xor(c, off, 64);
        if (lane == 0) atomicAdd(out, c * inv);
    }
}
#undef FOLD

extern "C" void kernel_launch(void* const* d_in, const int* in_sizes, int n_in,
                              void* d_out, int out_size, void* d_ws, size_t ws_size,
                              hipStream_t stream) {
    const float* fw  = (const float*)d_in[0];
    const float* bwv = (const float*)d_in[1];
    const float* p0  = (const float*)d_in[2];
    const float* p1  = (const float*)d_in[3];
    int N = in_sizes[0] / 3;               // 16384
    int nt = N / 32;                       // 512 tiles

    float* out = (float*)d_out;
    char* w = (char*)d_ws;
    int*           hist = (int*)w;            w += (size_t)4 * NBINS * 4;
    unsigned short* aux = (unsigned short*)w; w += (size_t)4 * N * 2;
    float4*   S    = (float4*)w;              w += (size_t)4 * N * 16;
    f16x8* Apanel  = (f16x8*)w;               w += (size_t)2 * nt * 64 * 16;
    float4*   TLo  = (float4*)w;              w += (size_t)2 * nt * 16;
    float4*   THi  = (float4*)w;

    binscan_kernel<<<4, 1024, 0, stream>>>(fw, bwv, p0, p1, hist, aux, out, N);
    scatter_kernel<<<dim3((N + 255) / 256, 1, 4), 256, 0, stream>>>(
        fw, bwv, p0, p1, hist, aux, S, N);
    panel_kernel<<<dim3(nt / 4, 1, 2), 256, 0, stream>>>(S, Apanel, TLo, THi, N, nt);
    chamfer_fused<<<dim3(nt, 1, 2), 64 * CW, 0, stream>>>(
        Apanel, S, TLo, THi, out, N, 1.0f / N, nt);
}

// Round 13
// 54.129 us; speedup vs baseline: 1.8895x; 1.8895x over previous
//
#include <hip/hip_runtime.h>

typedef _Float16 f16x8 __attribute__((ext_vector_type(8)));
typedef float f32x16 __attribute__((ext_vector_type(16)));

#define TRUNC_VAL 2.0f
#define NBINS 4096     // 16^3 Morton bins
#define RANK_BITS 14
#define GRID_LO  -4.0f
#define GRID_INV  2.0f
#define CW 8           // chamfer waves per block

// ---------------------------------------------------------------------------
// R13 = R11's chamfer rhythm + two repairs, R10's wide prep.
// R12 post-mortem: best-first phase 2 = 400cy serial chain per tile (MfmaUtil
// 2.7%, 86% idle); 4-block binscan = 4 CUs. Reverted both.
// Repairs vs R11 (whose defect was ONE stale block-wide ub):
//  - remaining segment groups processed in ascending-LB order
//  - re-ballot + wave-local ub refresh once PER GROUP (keeps dense ILP-2
//    inside a group; refresh cost amortized over 16 tiles)
//  - phase-2 survivors processed pairwise (ILP-2) off the ballot mask
// Exactness: ub = max_r clamp(partial min) >= max_r clamp(final) — any tile
// with lb >= ub cannot change any query's clamped min. absmax 0.0 expected.
// No device-scope fences (R2). No (256,1) (R6). Prep = R10's proven chain.
// ---------------------------------------------------------------------------

__device__ __forceinline__ unsigned mort4(unsigned v) {
    return (v & 1u) | ((v & 2u) << 2) | ((v & 4u) << 4) | ((v & 8u) << 6);
}

// set: 0 = p1 (fw targets), 1 = p0 (bw targets), 2 = p0+fw (fw queries),
//      3 = p0+fw-bw (bw queries)
__device__ __forceinline__ void load_point(int set, int i,
        const float* __restrict__ fw, const float* __restrict__ bw,
        const float* __restrict__ p0, const float* __restrict__ p1,
        float& x, float& y, float& z) {
    if (set == 0) { x = p1[3*i]; y = p1[3*i+1]; z = p1[3*i+2]; }
    else {
        x = p0[3*i]; y = p0[3*i+1]; z = p0[3*i+2];
        if (set >= 2) { x += fw[3*i]; y += fw[3*i+1]; z += fw[3*i+2]; }
        if (set == 3) { x -= bw[3*i]; y -= bw[3*i+1]; z -= bw[3*i+2]; }
    }
}

// --- S1: histogram + per-point (bin,rank); also zero the output scalar ----
__global__ void hist_kernel(const float* __restrict__ fw, const float* __restrict__ bw,
                            const float* __restrict__ p0, const float* __restrict__ p1,
                            int* __restrict__ hist, unsigned* __restrict__ aux,
                            float* __restrict__ out, int N) {
    int i = blockIdx.x * blockDim.x + threadIdx.x;
    int set = blockIdx.z;
    if (i == 0 && set == 0) out[0] = 0.0f;
    if (i >= N) return;
    float x, y, z; load_point(set, i, fw, bw, p0, p1, x, y, z);
    int xi = (int)((x - GRID_LO) * GRID_INV); xi = xi < 0 ? 0 : (xi > 15 ? 15 : xi);
    int yi = (int)((y - GRID_LO) * GRID_INV); yi = yi < 0 ? 0 : (yi > 15 ? 15 : yi);
    int zi = (int)((z - GRID_LO) * GRID_INV); zi = zi < 0 ? 0 : (zi > 15 ? 15 : zi);
    unsigned code = mort4(xi) | (mort4(yi) << 1) | (mort4(zi) << 2);   // < 4096
    int rank = atomicAdd(&hist[set * NBINS + code], 1);
    aux[(size_t)set * N + i] = (code << RANK_BITS) | (unsigned)rank;
}

// --- S2: exclusive scan of each set's 4096-bin histogram (1 block/set) ----
__global__ __launch_bounds__(1024) void scan_kernel(int* __restrict__ hist) {
    __shared__ int tmp[1024];
    int* h = hist + blockIdx.x * NBINS;
    int tid = threadIdx.x;
    int v[4], s = 0;
    #pragma unroll
    for (int k = 0; k < 4; ++k) { v[k] = h[tid * 4 + k]; s += v[k]; }
    tmp[tid] = s; __syncthreads();
    for (int off = 1; off < 1024; off <<= 1) {
        int x = (tid >= off) ? tmp[tid - off] : 0;
        __syncthreads();
        tmp[tid] += x;
        __syncthreads();
    }
    int excl = tmp[tid] - s;
    #pragma unroll
    for (int k = 0; k < 4; ++k) { int c = v[k]; h[tid * 4 + k] = excl; excl += c; }
}

// --- S3: scatter points into sorted float4 arrays (w = ||p||^2) -----------
__global__ void scatter_kernel(const float* __restrict__ fw, const float* __restrict__ bw,
                               const float* __restrict__ p0, const float* __restrict__ p1,
                               const int* __restrict__ hist, const unsigned* __restrict__ aux,
                               float4* __restrict__ S, int N) {
    int i = blockIdx.x * blockDim.x + threadIdx.x;
    int set = blockIdx.z;
    if (i >= N) return;
    unsigned av = aux[(size_t)set * N + i];
    unsigned code = av >> RANK_BITS;
    unsigned rank = av & ((1u << RANK_BITS) - 1u);
    int pos = hist[set * NBINS + code] + (int)rank;        // bijective
    float x, y, z; load_point(set, i, fw, bw, p0, p1, x, y, z);
    S[(size_t)set * N + pos] = make_float4(x, y, z, x*x + y*y + z*z);
}

// --- S4: A-panels (MFMA frags) + tile bounding boxes ----------------------
__global__ __launch_bounds__(256) void panel_kernel(const float4* __restrict__ S,
        f16x8* __restrict__ Apanel, float4* __restrict__ TLo, float4* __restrict__ THi,
        int N, int nt) {
    int z = blockIdx.z;
    int tile = blockIdx.x * 4 + (threadIdx.x >> 6);
    int lane = threadIdx.x & 63, r = lane & 31;
    bool hi = lane >= 32;
    float4 pt = S[(size_t)z * N + tile * 32 + r];
    float x = pt.x, y = pt.y, zc = pt.z;
    _Float16 xh = (_Float16)x, yh = (_Float16)y, zh = (_Float16)zc;
    _Float16 xl = (_Float16)(x  - (float)xh);
    _Float16 yl = (_Float16)(y  - (float)yh);
    _Float16 zl = (_Float16)(zc - (float)zh);
    float w = -0.5f * pt.w;
    _Float16 wh = (_Float16)w, wl = (_Float16)(w - (float)wh);
    f16x8 o;
    if (!hi) { o[0]=xh; o[1]=yh; o[2]=zh; o[3]=xh; o[4]=yh; o[5]=zh; o[6]=xl; o[7]=yl; }
    else {
        o[0]=zl; o[1]=wh; o[2]=wl;
        o[3]=(_Float16)0.0f; o[4]=(_Float16)0.0f; o[5]=(_Float16)0.0f;
        o[6]=(_Float16)0.0f; o[7]=(_Float16)0.0f;
    }
    Apanel[(size_t)z * nt * 64 + tile * 64 + lane] = o;
    float lx=x, ly=y, lz=zc, hx=x, hy=y, hz=zc;
    #pragma unroll
    for (int off = 1; off < 64; off <<= 1) {
        lx = fminf(lx, __shfl_xor(lx, off, 64));
        ly = fminf(ly, __shfl_xor(ly, off, 64));
        lz = fminf(lz, __shfl_xor(lz, off, 64));
        hx = fmaxf(hx, __shfl_xor(hx, off, 64));
        hy = fmaxf(hy, __shfl_xor(hy, off, 64));
        hz = fmaxf(hz, __shfl_xor(hz, off, 64));
    }
    if (lane == 0) {
        TLo[z * nt + tile] = make_float4(lx, ly, lz, 0.0f);
        THi[z * nt + tile] = make_float4(hx, hy, hz, 0.0f);
    }
}

#define FOLD(d)                                                     \
    _Pragma("unroll")                                               \
    for (int p = 0; p < 4; ++p) {                                   \
        m[p] = fmaxf(fmaxf(m[p], d[4*p  ]), d[4*p+1]);              \
        m[p] = fmaxf(fmaxf(m[p], d[4*p+2]), d[4*p+3]);              \
    }

// --- C: pruned chamfer. One block = (query tile, dir), 8 waves. -----------
__global__ __launch_bounds__(64 * CW, 4) void chamfer_fused(
        const f16x8* __restrict__ Apanel, const float4* __restrict__ S,
        const float4* __restrict__ TLo, const float4* __restrict__ THi,
        float* __restrict__ out, int N, float inv, int nt) {
    __shared__ float sM[CW][32];
    int tid = threadIdx.x;
    int lane = tid & 63, w = tid >> 6;
    int qt = blockIdx.x, z = blockIdx.z;
    int r = lane & 31; bool hi = lane >= 32;
    const f16x8* Ap = Apanel + (size_t)z * nt * 64;

    float4 q4 = S[(size_t)(2 + z) * N + qt * 32 + r];

    // B fragment (identical layout to the verified pack)
    float qx = q4.x, qy = q4.y, qz = q4.z;
    _Float16 xh = (_Float16)qx, yh = (_Float16)qy, zh = (_Float16)qz;
    _Float16 xl = (_Float16)(qx - (float)xh);
    _Float16 yl = (_Float16)(qy - (float)yh);
    _Float16 zl = (_Float16)(qz - (float)zh);
    f16x8 b;
    if (!hi) { b[0]=xh; b[1]=yh; b[2]=zh; b[3]=xl; b[4]=yl; b[5]=zl; b[6]=xh; b[7]=yh; }
    else {
        b[0]=zh; b[1]=(_Float16)1.0f; b[2]=(_Float16)1.0f;
        b[3]=(_Float16)0.0f; b[4]=(_Float16)0.0f; b[5]=(_Float16)0.0f;
        b[6]=(_Float16)0.0f; b[7]=(_Float16)0.0f;
    }

    // query-tile bounding box
    float qlx=qx, qly=qy, qlz=qz, qhx=qx, qhy=qy, qhz=qz;
    #pragma unroll
    for (int off = 1; off < 64; off <<= 1) {
        qlx = fminf(qlx, __shfl_xor(qlx, off, 64));
        qly = fminf(qly, __shfl_xor(qly, off, 64));
        qlz = fminf(qlz, __shfl_xor(qlz, off, 64));
        qhx = fmaxf(qhx, __shfl_xor(qhx, off, 64));
        qhy = fmaxf(qhy, __shfl_xor(qhy, off, 64));
        qhz = fmaxf(qhz, __shfl_xor(qhz, off, 64));
    }

    // lane owns tile (w + 8g)*16 + (lane&15), g = lane>>4
    int g = lane >> 4;
    int myTile = (w + CW * g) * 16 + (lane & 15);
    float4 lo = TLo[z * nt + myTile], hb = THi[z * nt + myTile];
    float gx = fmaxf(0.0f, fmaxf(lo.x - qhx, qlx - hb.x));
    float gy = fmaxf(0.0f, fmaxf(lo.y - qhy, qly - hb.y));
    float gz = fmaxf(0.0f, fmaxf(lo.z - qhz, qlz - hb.z));
    float lb = gx*gx + gy*gy + gz*gz;

    // per-segment min LB (within each 16-lane group) + all 4 group LBs
    float slb = lb;
    #pragma unroll
    for (int off = 1; off < 16; off <<= 1) slb = fminf(slb, __shfl_xor(slb, off, 64));
    float sv0 = __shfl(slb,  0, 64);
    float sv1 = __shfl(slb, 16, 64);
    float sv2 = __shfl(slb, 32, 64);
    float sv3 = __shfl(slb, 48, 64);
    // wave-local nearest group
    int s0g = 0; float s0v = sv0;
    if (sv1 < s0v) { s0v = sv1; s0g = 1; }
    if (sv2 < s0v) { s0v = sv2; s0g = 2; }
    if (sv3 < s0v) { s0v = sv3; s0g = 3; }

    float m[4] = { -3.0e38f, -3.0e38f, -3.0e38f, -3.0e38f };
    const f32x16 zero = {};

    // ---- phase 1: dense ILP-2 sweep of the wave's nearest segment ----
    int tb0 = (w + CW * s0g) * 16;
    f16x8 a0 = Ap[(size_t)(tb0    ) * 64 + lane];
    f16x8 a1 = Ap[(size_t)(tb0 + 1) * 64 + lane];
    for (int t = 0; t < 16; t += 2) {
        f16x8 c0 = a0, c1 = a1;
        int t2 = (t + 2 < 16) ? t + 2 : t;
        int t3 = (t + 3 < 16) ? t + 3 : t + 1;
        a0 = Ap[(size_t)(tb0 + t2) * 64 + lane];
        a1 = Ap[(size_t)(tb0 + t3) * 64 + lane];
        f32x16 d0 = __builtin_amdgcn_mfma_f32_32x32x16_f16(c0, b, zero, 0, 0, 0);
        f32x16 d1 = __builtin_amdgcn_mfma_f32_32x32x16_f16(c1, b, zero, 0, 0, 0);
        FOLD(d0) FOLD(d1)
    }
    if (g == s0g) lb = 3.0e38f;               // phase-1 tiles processed

    // ---- block-wide ub from all 8 waves' phase-1 results ----
    float v = fmaxf(fmaxf(m[0], m[1]), fmaxf(m[2], m[3]));
    v = fmaxf(v, __shfl_xor(v, 32, 64));
    if (lane < 32) sM[w][lane] = v;
    __syncthreads();
    float mx = sM[0][r];
    #pragma unroll
    for (int ww = 1; ww < CW; ++ww) mx = fmaxf(mx, sM[ww][r]);
    float d2c = fmaf(-2.0f, mx, q4.w);
    d2c = fmaxf(d2c, 0.0f); d2c = fminf(d2c, TRUNC_VAL);
    float ub = d2c;
    #pragma unroll
    for (int off = 1; off < 64; off <<= 1) ub = fmaxf(ub, __shfl_xor(ub, off, 64));
    __syncthreads();                          // sM free for reuse

    // ---- phase 2: remaining 3 groups, ascending LB, ub refresh per group -
    int done = 1 << s0g;
    for (int pass = 0; pass < 3; ++pass) {
        float best = 3.0e38f; int bk = 0;
        if (!(done & 1) && sv0 < best) { best = sv0; bk = 0; }
        if (!(done & 2) && sv1 < best) { best = sv1; bk = 1; }
        if (!(done & 4) && sv2 < best) { best = sv2; bk = 2; }
        if (!(done & 8) && sv3 < best) { best = sv3; bk = 3; }
        if (best >= ub) break;
        done |= 1 << bk;
        int tb = (w + CW * bk) * 16;
        unsigned long long bal = __ballot(lb < ub);
        unsigned msk = (unsigned)((bal >> (16 * bk)) & 0xFFFFull);
        while (msk) {
            int t0 = __builtin_ctz(msk); msk &= msk - 1;
            int t1 = -1;
            if (msk) { t1 = __builtin_ctz(msk); msk &= msk - 1; }
            f16x8 c0 = Ap[(size_t)(tb + t0) * 64 + lane];
            if (t1 >= 0) {
                f16x8 c1 = Ap[(size_t)(tb + t1) * 64 + lane];
                f32x16 d0 = __builtin_amdgcn_mfma_f32_32x32x16_f16(c0, b, zero, 0, 0, 0);
                f32x16 d1 = __builtin_amdgcn_mfma_f32_32x32x16_f16(c1, b, zero, 0, 0, 0);
                FOLD(d0) FOLD(d1)
            } else {
                f32x16 d0 = __builtin_amdgcn_mfma_f32_32x32x16_f16(c0, b, zero, 0, 0, 0);
                FOLD(d0)
            }
        }
        // wave-local ub refresh (valid: partial min >= final min)
        float vv = fmaxf(fmaxf(m[0], m[1]), fmaxf(m[2], m[3]));
        vv = fmaxf(vv, __shfl_xor(vv, 32, 64));
        float dd = fmaf(-2.0f, vv, q4.w);
        dd = fmaxf(dd, 0.0f); dd = fminf(dd, TRUNC_VAL);
        #pragma unroll
        for (int off = 1; off < 64; off <<= 1) dd = fmaxf(dd, __shfl_xor(dd, off, 64));
        ub = fminf(ub, dd);
    }

    // ---- final combine, truncated chamfer, block sum, one atomicAdd ----
    v = fmaxf(fmaxf(m[0], m[1]), fmaxf(m[2], m[3]));
    v = fmaxf(v, __shfl_xor(v, 32, 64));
    if (lane < 32) sM[w][lane] = v;
    __syncthreads();
    if (w == 0) {
        float mx2 = sM[0][r];
        #pragma unroll
        for (int ww = 1; ww < CW; ++ww) mx2 = fmaxf(mx2, sM[ww][r]);
        float d2 = fmaf(-2.0f, mx2, q4.w);
        d2 = fmaxf(d2, 0.0f);
        float dc = fminf(d2, TRUNC_VAL);
        float c = (lane < 32) ? dc : 0.0f;
        #pragma unroll
        for (int off = 1; off < 64; off <<= 1) c += __shfl_xor(c, off, 64);
        if (lane == 0) atomicAdd(out, c * inv);
    }
}
#undef FOLD

extern "C" void kernel_launch(void* const* d_in, const int* in_sizes, int n_in,
                              void* d_out, int out_size, void* d_ws, size_t ws_size,
                              hipStream_t stream) {
    const float* fw  = (const float*)d_in[0];
    const float* bwv = (const float*)d_in[1];
    const float* p0  = (const float*)d_in[2];
    const float* p1  = (const float*)d_in[3];
    int N = in_sizes[0] / 3;               // 16384
    int nt = N / 32;                       // 512 tiles

    float* out = (float*)d_out;
    char* w = (char*)d_ws;
    int*      hist = (int*)w;       w += (size_t)4 * NBINS * 4;
    unsigned* aux  = (unsigned*)w;  w += (size_t)4 * N * 4;
    float4*   S    = (float4*)w;    w += (size_t)4 * N * 16;
    f16x8* Apanel  = (f16x8*)w;     w += (size_t)2 * nt * 64 * 16;
    float4*   TLo  = (float4*)w;    w += (size_t)2 * nt * 16;
    float4*   THi  = (float4*)w;

    hipMemsetAsync(hist, 0, (size_t)4 * NBINS * 4, stream);
    dim3 gp((N + 255) / 256, 1, 4);
    hist_kernel<<<gp, 256, 0, stream>>>(fw, bwv, p0, p1, hist, aux, out, N);
    scan_kernel<<<4, 1024, 0, stream>>>(hist);
    scatter_kernel<<<gp, 256, 0, stream>>>(fw, bwv, p0, p1, hist, aux, S, N);
    panel_kernel<<<dim3(nt / 4, 1, 2), 256, 0, stream>>>(S, Apanel, TLo, THi, N, nt);
    chamfer_fused<<<dim3(nt, 1, 2), 64 * CW, 0, stream>>>(
        Apanel, S, TLo, THi, out, N, 1.0f / N, nt);
}

// Round 14
// 51.157 us; speedup vs baseline: 1.9992x; 1.0581x over previous
//
#include <hip/hip_runtime.h>

typedef _Float16 f16x8 __attribute__((ext_vector_type(8)));
typedef float f32x16 __attribute__((ext_vector_type(16)));

#define TRUNC_VAL 2.0f
#define NBINS 4096     // 16^3 Morton bins
#define RANK_BITS 14
#define GRID_LO  -4.0f
#define GRID_INV  2.0f
#define CW 8           // chamfer waves per block

// ---------------------------------------------------------------------------
// R14 = R13 logic (absmax 0.0) with the chamfer's MEMORY SCHEDULE fixed.
// R13 post-mortem: the pruned family is latency-bound on data-dependent
// A-frag gathers (VGPR=28, MfmaUtil 2.7%, ~86% idle) — each wave eats a
// ~600cy miss every 1-2 tiles. Fix: batch loads into registers.
//  - phase 1: two 8-deep load batches (one stall each instead of 8)
//  - phase 2: 4-deep batches off the ballot mask; tail padded with duplicate
//    tiles (fmax(x,x)=x -> bit-identical, branch-free)
//  - __launch_bounds__(512,4): <=128 VGPR, 4 waves/SIMD to cross-cover stalls
// Skip exactness unchanged: lb >= ub >= clamp(final) can't change any query.
// No device-scope fences (R2). No best-first serial chains (R12).
// ---------------------------------------------------------------------------

__device__ __forceinline__ unsigned mort4(unsigned v) {
    return (v & 1u) | ((v & 2u) << 2) | ((v & 4u) << 4) | ((v & 8u) << 6);
}

// set: 0 = p1 (fw targets), 1 = p0 (bw targets), 2 = p0+fw (fw queries),
//      3 = p0+fw-bw (bw queries)
__device__ __forceinline__ void load_point(int set, int i,
        const float* __restrict__ fw, const float* __restrict__ bw,
        const float* __restrict__ p0, const float* __restrict__ p1,
        float& x, float& y, float& z) {
    if (set == 0) { x = p1[3*i]; y = p1[3*i+1]; z = p1[3*i+2]; }
    else {
        x = p0[3*i]; y = p0[3*i+1]; z = p0[3*i+2];
        if (set >= 2) { x += fw[3*i]; y += fw[3*i+1]; z += fw[3*i+2]; }
        if (set == 3) { x -= bw[3*i]; y -= bw[3*i+1]; z -= bw[3*i+2]; }
    }
}

// --- S1: histogram + per-point (bin,rank); also zero the output scalar ----
__global__ void hist_kernel(const float* __restrict__ fw, const float* __restrict__ bw,
                            const float* __restrict__ p0, const float* __restrict__ p1,
                            int* __restrict__ hist, unsigned* __restrict__ aux,
                            float* __restrict__ out, int N) {
    int i = blockIdx.x * blockDim.x + threadIdx.x;
    int set = blockIdx.z;
    if (i == 0 && set == 0) out[0] = 0.0f;
    if (i >= N) return;
    float x, y, z; load_point(set, i, fw, bw, p0, p1, x, y, z);
    int xi = (int)((x - GRID_LO) * GRID_INV); xi = xi < 0 ? 0 : (xi > 15 ? 15 : xi);
    int yi = (int)((y - GRID_LO) * GRID_INV); yi = yi < 0 ? 0 : (yi > 15 ? 15 : yi);
    int zi = (int)((z - GRID_LO) * GRID_INV); zi = zi < 0 ? 0 : (zi > 15 ? 15 : zi);
    unsigned code = mort4(xi) | (mort4(yi) << 1) | (mort4(zi) << 2);   // < 4096
    int rank = atomicAdd(&hist[set * NBINS + code], 1);
    aux[(size_t)set * N + i] = (code << RANK_BITS) | (unsigned)rank;
}

// --- S2: exclusive scan of each set's 4096-bin histogram (1 block/set) ----
__global__ __launch_bounds__(1024) void scan_kernel(int* __restrict__ hist) {
    __shared__ int tmp[1024];
    int* h = hist + blockIdx.x * NBINS;
    int tid = threadIdx.x;
    int v[4], s = 0;
    #pragma unroll
    for (int k = 0; k < 4; ++k) { v[k] = h[tid * 4 + k]; s += v[k]; }
    tmp[tid] = s; __syncthreads();
    for (int off = 1; off < 1024; off <<= 1) {
        int x = (tid >= off) ? tmp[tid - off] : 0;
        __syncthreads();
        tmp[tid] += x;
        __syncthreads();
    }
    int excl = tmp[tid] - s;
    #pragma unroll
    for (int k = 0; k < 4; ++k) { int c = v[k]; h[tid * 4 + k] = excl; excl += c; }
}

// --- S3: scatter points into sorted float4 arrays (w = ||p||^2) -----------
__global__ void scatter_kernel(const float* __restrict__ fw, const float* __restrict__ bw,
                               const float* __restrict__ p0, const float* __restrict__ p1,
                               const int* __restrict__ hist, const unsigned* __restrict__ aux,
                               float4* __restrict__ S, int N) {
    int i = blockIdx.x * blockDim.x + threadIdx.x;
    int set = blockIdx.z;
    if (i >= N) return;
    unsigned av = aux[(size_t)set * N + i];
    unsigned code = av >> RANK_BITS;
    unsigned rank = av & ((1u << RANK_BITS) - 1u);
    int pos = hist[set * NBINS + code] + (int)rank;        // bijective
    float x, y, z; load_point(set, i, fw, bw, p0, p1, x, y, z);
    S[(size_t)set * N + pos] = make_float4(x, y, z, x*x + y*y + z*z);
}

// --- S4: A-panels (MFMA frags) + tile bounding boxes ----------------------
__global__ __launch_bounds__(256) void panel_kernel(const float4* __restrict__ S,
        f16x8* __restrict__ Apanel, float4* __restrict__ TLo, float4* __restrict__ THi,
        int N, int nt) {
    int z = blockIdx.z;
    int tile = blockIdx.x * 4 + (threadIdx.x >> 6);
    int lane = threadIdx.x & 63, r = lane & 31;
    bool hi = lane >= 32;
    float4 pt = S[(size_t)z * N + tile * 32 + r];
    float x = pt.x, y = pt.y, zc = pt.z;
    _Float16 xh = (_Float16)x, yh = (_Float16)y, zh = (_Float16)zc;
    _Float16 xl = (_Float16)(x  - (float)xh);
    _Float16 yl = (_Float16)(y  - (float)yh);
    _Float16 zl = (_Float16)(zc - (float)zh);
    float w = -0.5f * pt.w;
    _Float16 wh = (_Float16)w, wl = (_Float16)(w - (float)wh);
    f16x8 o;
    if (!hi) { o[0]=xh; o[1]=yh; o[2]=zh; o[3]=xh; o[4]=yh; o[5]=zh; o[6]=xl; o[7]=yl; }
    else {
        o[0]=zl; o[1]=wh; o[2]=wl;
        o[3]=(_Float16)0.0f; o[4]=(_Float16)0.0f; o[5]=(_Float16)0.0f;
        o[6]=(_Float16)0.0f; o[7]=(_Float16)0.0f;
    }
    Apanel[(size_t)z * nt * 64 + tile * 64 + lane] = o;
    float lx=x, ly=y, lz=zc, hx=x, hy=y, hz=zc;
    #pragma unroll
    for (int off = 1; off < 64; off <<= 1) {
        lx = fminf(lx, __shfl_xor(lx, off, 64));
        ly = fminf(ly, __shfl_xor(ly, off, 64));
        lz = fminf(lz, __shfl_xor(lz, off, 64));
        hx = fmaxf(hx, __shfl_xor(hx, off, 64));
        hy = fmaxf(hy, __shfl_xor(hy, off, 64));
        hz = fmaxf(hz, __shfl_xor(hz, off, 64));
    }
    if (lane == 0) {
        TLo[z * nt + tile] = make_float4(lx, ly, lz, 0.0f);
        THi[z * nt + tile] = make_float4(hx, hy, hz, 0.0f);
    }
}

#define FOLD(d)                                                     \
    _Pragma("unroll")                                               \
    for (int p = 0; p < 4; ++p) {                                   \
        m[p] = fmaxf(fmaxf(m[p], d[4*p  ]), d[4*p+1]);              \
        m[p] = fmaxf(fmaxf(m[p], d[4*p+2]), d[4*p+3]);              \
    }

// --- C: pruned chamfer with register-batched loads. -----------------------
__global__ __launch_bounds__(64 * CW, 4) void chamfer_fused(
        const f16x8* __restrict__ Apanel, const float4* __restrict__ S,
        const float4* __restrict__ TLo, const float4* __restrict__ THi,
        float* __restrict__ out, int N, float inv, int nt) {
    __shared__ float sM[CW][32];
    int tid = threadIdx.x;
    int lane = tid & 63, w = tid >> 6;
    int qt = blockIdx.x, z = blockIdx.z;
    int r = lane & 31; bool hi = lane >= 32;
    const f16x8* Ap = Apanel + (size_t)z * nt * 64;

    float4 q4 = S[(size_t)(2 + z) * N + qt * 32 + r];

    // B fragment (identical layout to the verified pack)
    float qx = q4.x, qy = q4.y, qz = q4.z;
    _Float16 xh = (_Float16)qx, yh = (_Float16)qy, zh = (_Float16)qz;
    _Float16 xl = (_Float16)(qx - (float)xh);
    _Float16 yl = (_Float16)(qy - (float)yh);
    _Float16 zl = (_Float16)(qz - (float)zh);
    f16x8 b;
    if (!hi) { b[0]=xh; b[1]=yh; b[2]=zh; b[3]=xl; b[4]=yl; b[5]=zl; b[6]=xh; b[7]=yh; }
    else {
        b[0]=zh; b[1]=(_Float16)1.0f; b[2]=(_Float16)1.0f;
        b[3]=(_Float16)0.0f; b[4]=(_Float16)0.0f; b[5]=(_Float16)0.0f;
        b[6]=(_Float16)0.0f; b[7]=(_Float16)0.0f;
    }

    // query-tile bounding box
    float qlx=qx, qly=qy, qlz=qz, qhx=qx, qhy=qy, qhz=qz;
    #pragma unroll
    for (int off = 1; off < 64; off <<= 1) {
        qlx = fminf(qlx, __shfl_xor(qlx, off, 64));
        qly = fminf(qly, __shfl_xor(qly, off, 64));
        qlz = fminf(qlz, __shfl_xor(qlz, off, 64));
        qhx = fmaxf(qhx, __shfl_xor(qhx, off, 64));
        qhy = fmaxf(qhy, __shfl_xor(qhy, off, 64));
        qhz = fmaxf(qhz, __shfl_xor(qhz, off, 64));
    }

    // lane owns tile (w + 8g)*16 + (lane&15), g = lane>>4
    int g = lane >> 4;
    int myTile = (w + CW * g) * 16 + (lane & 15);
    float4 lo = TLo[z * nt + myTile], hb = THi[z * nt + myTile];
    float gx = fmaxf(0.0f, fmaxf(lo.x - qhx, qlx - hb.x));
    float gy = fmaxf(0.0f, fmaxf(lo.y - qhy, qly - hb.y));
    float gz = fmaxf(0.0f, fmaxf(lo.z - qhz, qlz - hb.z));
    float lb = gx*gx + gy*gy + gz*gz;

    // per-segment min LB (within each 16-lane group) + all 4 group LBs
    float slb = lb;
    #pragma unroll
    for (int off = 1; off < 16; off <<= 1) slb = fminf(slb, __shfl_xor(slb, off, 64));
    float sv0 = __shfl(slb,  0, 64);
    float sv1 = __shfl(slb, 16, 64);
    float sv2 = __shfl(slb, 32, 64);
    float sv3 = __shfl(slb, 48, 64);
    int s0g = 0; float s0v = sv0;
    if (sv1 < s0v) { s0v = sv1; s0g = 1; }
    if (sv2 < s0v) { s0v = sv2; s0g = 2; }
    if (sv3 < s0v) { s0v = sv3; s0g = 3; }

    float m[4] = { -3.0e38f, -3.0e38f, -3.0e38f, -3.0e38f };
    const f32x16 zero = {};

    // ---- phase 1: nearest segment, two 8-deep register load batches ----
    int tb0 = (w + CW * s0g) * 16;
    #pragma unroll 1
    for (int half = 0; half < 2; ++half) {
        const f16x8* Ah = Ap + (size_t)(tb0 + half * 8) * 64 + lane;
        f16x8 a0_ = Ah[0 * 64], a1_ = Ah[1 * 64], a2_ = Ah[2 * 64], a3_ = Ah[3 * 64];
        f16x8 a4_ = Ah[4 * 64], a5_ = Ah[5 * 64], a6_ = Ah[6 * 64], a7_ = Ah[7 * 64];
        f32x16 d0 = __builtin_amdgcn_mfma_f32_32x32x16_f16(a0_, b, zero, 0, 0, 0);
        f32x16 d1 = __builtin_amdgcn_mfma_f32_32x32x16_f16(a1_, b, zero, 0, 0, 0);
        FOLD(d0) FOLD(d1)
        d0 = __builtin_amdgcn_mfma_f32_32x32x16_f16(a2_, b, zero, 0, 0, 0);
        d1 = __builtin_amdgcn_mfma_f32_32x32x16_f16(a3_, b, zero, 0, 0, 0);
        FOLD(d0) FOLD(d1)
        d0 = __builtin_amdgcn_mfma_f32_32x32x16_f16(a4_, b, zero, 0, 0, 0);
        d1 = __builtin_amdgcn_mfma_f32_32x32x16_f16(a5_, b, zero, 0, 0, 0);
        FOLD(d0) FOLD(d1)
        d0 = __builtin_amdgcn_mfma_f32_32x32x16_f16(a6_, b, zero, 0, 0, 0);
        d1 = __builtin_amdgcn_mfma_f32_32x32x16_f16(a7_, b, zero, 0, 0, 0);
        FOLD(d0) FOLD(d1)
    }
    if (g == s0g) lb = 3.0e38f;               // phase-1 tiles processed

    // ---- block-wide ub from all 8 waves' phase-1 results ----
    float v = fmaxf(fmaxf(m[0], m[1]), fmaxf(m[2], m[3]));
    v = fmaxf(v, __shfl_xor(v, 32, 64));
    if (lane < 32) sM[w][lane] = v;
    __syncthreads();
    float mx = sM[0][r];
    #pragma unroll
    for (int ww = 1; ww < CW; ++ww) mx = fmaxf(mx, sM[ww][r]);
    float d2c = fmaf(-2.0f, mx, q4.w);
    d2c = fmaxf(d2c, 0.0f); d2c = fminf(d2c, TRUNC_VAL);
    float ub = d2c;
    #pragma unroll
    for (int off = 1; off < 64; off <<= 1) ub = fmaxf(ub, __shfl_xor(ub, off, 64));
    __syncthreads();                          // sM free for reuse

    // ---- phase 2: remaining groups, ascending LB, 4-deep load batches ----
    int done = 1 << s0g;
    for (int pass = 0; pass < 3; ++pass) {
        float best = 3.0e38f; int bk = 0;
        if (!(done & 1) && sv0 < best) { best = sv0; bk = 0; }
        if (!(done & 2) && sv1 < best) { best = sv1; bk = 1; }
        if (!(done & 4) && sv2 < best) { best = sv2; bk = 2; }
        if (!(done & 8) && sv3 < best) { best = sv3; bk = 3; }
        if (best >= ub) break;
        done |= 1 << bk;
        int tb = (w + CW * bk) * 16;
        unsigned long long bal = __ballot(lb < ub);
        unsigned msk = (unsigned)((bal >> (16 * bk)) & 0xFFFFull);
        while (msk) {
            int t0 = __builtin_ctz(msk); msk &= msk - 1;
            int t1 = t0, t2 = t0, t3 = t0;     // dup pad: fmax(x,x)=x, exact
            if (msk) { t1 = __builtin_ctz(msk); msk &= msk - 1; }
            if (msk) { t2 = __builtin_ctz(msk); msk &= msk - 1; }
            if (msk) { t3 = __builtin_ctz(msk); msk &= msk - 1; }
            f16x8 c0 = Ap[(size_t)(tb + t0) * 64 + lane];
            f16x8 c1 = Ap[(size_t)(tb + t1) * 64 + lane];
            f16x8 c2 = Ap[(size_t)(tb + t2) * 64 + lane];
            f16x8 c3 = Ap[(size_t)(tb + t3) * 64 + lane];
            f32x16 d0 = __builtin_amdgcn_mfma_f32_32x32x16_f16(c0, b, zero, 0, 0, 0);
            f32x16 d1 = __builtin_amdgcn_mfma_f32_32x32x16_f16(c1, b, zero, 0, 0, 0);
            FOLD(d0) FOLD(d1)
            d0 = __builtin_amdgcn_mfma_f32_32x32x16_f16(c2, b, zero, 0, 0, 0);
            d1 = __builtin_amdgcn_mfma_f32_32x32x16_f16(c3, b, zero, 0, 0, 0);
            FOLD(d0) FOLD(d1)
        }
        // wave-local ub refresh (valid: partial min >= final min)
        float vv = fmaxf(fmaxf(m[0], m[1]), fmaxf(m[2], m[3]));
        vv = fmaxf(vv, __shfl_xor(vv, 32, 64));
        float dd = fmaf(-2.0f, vv, q4.w);
        dd = fmaxf(dd, 0.0f); dd = fminf(dd, TRUNC_VAL);
        #pragma unroll
        for (int off = 1; off < 64; off <<= 1) dd = fmaxf(dd, __shfl_xor(dd, off, 64));
        ub = fminf(ub, dd);
    }

    // ---- final combine, truncated chamfer, block sum, one atomicAdd ----
    v = fmaxf(fmaxf(m[0], m[1]), fmaxf(m[2], m[3]));
    v = fmaxf(v, __shfl_xor(v, 32, 64));
    if (lane < 32) sM[w][lane] = v;
    __syncthreads();
    if (w == 0) {
        float mx2 = sM[0][r];
        #pragma unroll
        for (int ww = 1; ww < CW; ++ww) mx2 = fmaxf(mx2, sM[ww][r]);
        float d2 = fmaf(-2.0f, mx2, q4.w);
        d2 = fmaxf(d2, 0.0f);
        float dc = fminf(d2, TRUNC_VAL);
        float c = (lane < 32) ? dc : 0.0f;
        #pragma unroll
        for (int off = 1; off < 64; off <<= 1) c += __shfl_xor(c, off, 64);
        if (lane == 0) atomicAdd(out, c * inv);
    }
}
#undef FOLD

extern "C" void kernel_launch(void* const* d_in, const int* in_sizes, int n_in,
                              void* d_out, int out_size, void* d_ws, size_t ws_size,
                              hipStream_t stream) {
    const float* fw  = (const float*)d_in[0];
    const float* bwv = (const float*)d_in[1];
    const float* p0  = (const float*)d_in[2];
    const float* p1  = (const float*)d_in[3];
    int N = in_sizes[0] / 3;               // 16384
    int nt = N / 32;                       // 512 tiles

    float* out = (float*)d_out;
    char* w = (char*)d_ws;
    int*      hist = (int*)w;       w += (size_t)4 * NBINS * 4;
    unsigned* aux  = (unsigned*)w;  w += (size_t)4 * N * 4;
    float4*   S    = (float4*)w;    w += (size_t)4 * N * 16;
    f16x8* Apanel  = (f16x8*)w;     w += (size_t)2 * nt * 64 * 16;
    float4*   TLo  = (float4*)w;    w += (size_t)2 * nt * 16;
    float4*   THi  = (float4*)w;

    hipMemsetAsync(hist, 0, (size_t)4 * NBINS * 4, stream);
    dim3 gp((N + 255) / 256, 1, 4);
    hist_kernel<<<gp, 256, 0, stream>>>(fw, bwv, p0, p1, hist, aux, out, N);
    scan_kernel<<<4, 1024, 0, stream>>>(hist);
    scatter_kernel<<<gp, 256, 0, stream>>>(fw, bwv, p0, p1, hist, aux, S, N);
    panel_kernel<<<dim3(nt / 4, 1, 2), 256, 0, stream>>>(S, Apanel, TLo, THi, N, nt);
    chamfer_fused<<<dim3(nt, 1, 2), 64 * CW, 0, stream>>>(
        Apanel, S, TLo, THi, out, N, 1.0f / N, nt);
}

// Round 15
// 28.703 us; speedup vs baseline: 3.5632x; 1.7823x over previous
//
#include <hip/hip_runtime.h>

typedef _Float16 f16x8 __attribute__((ext_vector_type(8)));
typedef float f32x16 __attribute__((ext_vector_type(16)));

#define TRUNC_VAL 2.0f
#define TPS 16     // A-tiles per segment (LDS-resident); NSEG = NT/TPS
#define NSEG 32    // segments for N=16384
#define WPB 4      // waves per block
#define BPT 4      // query (B) tiles per wave: 4 MFMAs per A-frag read

// ---------------------------------------------------------------------------
// R15 = exact revert to R8, the measured champion (28.6us, absmax 0.0).
// Ledger: R4 fused pack (2-kernel), R5 ILP-4 named accumulators (+23%),
// R8 BPT=4 off the 256-reg allocation boundary (+7%). Nulls/negatives:
// launch-count (R3/R4), zero-remat barrier (R7), (256,1) -> 88-VGPR AGPR
// schedule (R6, -23%), 4-wave/ILP-2 (R9), device-scope fences (R2, -3x),
// spatial pruning family (R10-R14: best 51us — mean work pruned 76% but
// per-wave max work unpruned; fringe-tile tail dominates the dispatch).
//
// Fragment layout (verified, absmax 0.0):
//   v_mfma_f32_32x32x16_f16, lane l of tile t at frag[t*64+l],
//   row/col = l&31, k = 8*(l>>5)+i.  hi/lo fp16 split, ~22-bit precision:
//   A (target j): [xh yh zh | xh yh zh | xl yl zl | wh wl | 0...] w=-0.5||y||^2
//   B (query  i): [xh yh zh | xl yl zl | xh yh zh | 1  1  | 0...]
//   => dot = q.y - 0.5||y||^2
// ---------------------------------------------------------------------------
__global__ __launch_bounds__(64 * WPB, 2) void chamfer_mfma_kernel(
    const float* __restrict__ fw, const float* __restrict__ bwv,
    const float* __restrict__ p0, const float* __restrict__ p1,
    float* __restrict__ Pfw, float* __restrict__ Pbw,
    float* __restrict__ out, int N) {
    __shared__ f16x8 Alds[TPS * 64];           // 16 KB: the block's A segment

    int lane = threadIdx.x & 63;
    int wave = threadIdx.x >> 6;
    int r    = lane & 31;
    bool hi  = lane >= 32;
    int col  = blockIdx.x * WPB + wave;        // query column: 128 queries/wave
    int seg  = blockIdx.y;                     // target segment (block-shared)
    int z    = blockIdx.z;
    float* __restrict__ P = z ? Pbw : Pfw;

    // out[0] = 0 once per launch; stream-ordered before reduce's atomicAdds.
    if (threadIdx.x == 0 && blockIdx.x == 0 && blockIdx.y == 0 && z == 0)
        out[0] = 0.0f;

    // ---- build B fragments in registers (once per wave) ----
    f16x8 b[BPT];
    #pragma unroll
    for (int c = 0; c < BPT; ++c) {
        int i = (col * BPT + c) * 32 + r;
        float qx = p0[3*i]   + fw[3*i];
        float qy = p0[3*i+1] + fw[3*i+1];
        float qz = p0[3*i+2] + fw[3*i+2];
        if (z) { qx -= bwv[3*i]; qy -= bwv[3*i+1]; qz -= bwv[3*i+2]; }
        _Float16 xh = (_Float16)qx, yh = (_Float16)qy, zh = (_Float16)qz;
        _Float16 xl = (_Float16)(qx - (float)xh);
        _Float16 yl = (_Float16)(qy - (float)yh);
        _Float16 zl = (_Float16)(qz - (float)zh);
        f16x8 o;
        if (!hi) { o[0]=xh; o[1]=yh; o[2]=zh; o[3]=xl; o[4]=yl; o[5]=zl; o[6]=xh; o[7]=yh; }
        else {
            o[0]=zh; o[1]=(_Float16)1.0f; o[2]=(_Float16)1.0f;
            o[3]=(_Float16)0.0f; o[4]=(_Float16)0.0f; o[5]=(_Float16)0.0f;
            o[6]=(_Float16)0.0f; o[7]=(_Float16)0.0f;
        }
        b[c] = o;
    }

    // ---- build A fragments into LDS (each wave packs TPS/WPB = 4 tiles) ----
    const float* __restrict__ tgt = z ? p0 : p1;
    #pragma unroll
    for (int lt = 0; lt < TPS / WPB; ++lt) {
        int t = wave * (TPS / WPB) + lt;
        int j = (seg * TPS + t) * 32 + r;
        float x = tgt[3*j], y = tgt[3*j+1], zc = tgt[3*j+2];
        _Float16 xh = (_Float16)x, yh = (_Float16)y, zh = (_Float16)zc;
        _Float16 xl = (_Float16)(x  - (float)xh);
        _Float16 yl = (_Float16)(y  - (float)yh);
        _Float16 zl = (_Float16)(zc - (float)zh);
        float w = -0.5f * (x*x + y*y + zc*zc);
        _Float16 wh = (_Float16)w, wl = (_Float16)(w - (float)wh);
        f16x8 o;
        if (!hi) { o[0]=xh; o[1]=yh; o[2]=zh; o[3]=xh; o[4]=yh; o[5]=zh; o[6]=xl; o[7]=yl; }
        else {
            o[0]=zl; o[1]=wh; o[2]=wl;
            o[3]=(_Float16)0.0f; o[4]=(_Float16)0.0f; o[5]=(_Float16)0.0f;
            o[6]=(_Float16)0.0f; o[7]=(_Float16)0.0f;
        }
        Alds[t * 64 + lane] = o;
    }
    __syncthreads();

    // ---- MFMA loop: 4 independent MFMAs in flight, then fold ----
    float m[BPT][4];
    #pragma unroll
    for (int c = 0; c < BPT; ++c)
        #pragma unroll
        for (int p = 0; p < 4; ++p) m[c][p] = -3.0e38f;

    const f32x16 zero = {};
    f16x8 a = Alds[lane];

#define FOLD(c, d)                                                  \
    _Pragma("unroll")                                               \
    for (int p = 0; p < 4; ++p) {                                   \
        m[c][p] = fmaxf(fmaxf(m[c][p], d[4*p  ]), d[4*p+1]);        \
        m[c][p] = fmaxf(fmaxf(m[c][p], d[4*p+2]), d[4*p+3]);        \
    }

    for (int t = 0; t < TPS; ++t) {
        f16x8 a_cur = a;
        int tn = (t + 1 < TPS) ? t + 1 : t;
        a = Alds[tn * 64 + lane];              // prefetch next A-frag
        f32x16 d0 = __builtin_amdgcn_mfma_f32_32x32x16_f16(a_cur, b[0], zero, 0, 0, 0);
        f32x16 d1 = __builtin_amdgcn_mfma_f32_32x32x16_f16(a_cur, b[1], zero, 0, 0, 0);
        f32x16 d2 = __builtin_amdgcn_mfma_f32_32x32x16_f16(a_cur, b[2], zero, 0, 0, 0);
        f32x16 d3 = __builtin_amdgcn_mfma_f32_32x32x16_f16(a_cur, b[3], zero, 0, 0, 0);
        FOLD(0, d0) FOLD(1, d1) FOLD(2, d2) FOLD(3, d3)
    }
#undef FOLD

    #pragma unroll
    for (int c = 0; c < BPT; ++c) {
        float v = fmaxf(fmaxf(m[c][0], m[c][1]), fmaxf(m[c][2], m[c][3]));
        v = fmaxf(v, __shfl_xor(v, 32, 64));   // fold the two row-halves
        if (lane < 32) P[(size_t)seg * N + col * (32 * BPT) + c * 32 + lane] = v;
    }
}

// ---------------------------------------------------------------------------
// Combine segment maxima, form truncated chamfer per query, mean-reduce.
// ---------------------------------------------------------------------------
__global__ __launch_bounds__(256) void reduce_kernel(
    const float* __restrict__ fw, const float* __restrict__ bwv,
    const float* __restrict__ p0,
    const float* __restrict__ Pfw, const float* __restrict__ Pbw,
    float* __restrict__ out, int N, float inv) {
    int z = blockIdx.z;
    const float* __restrict__ part = z ? Pbw : Pfw;

    int i = blockIdx.x * blockDim.x + threadIdx.x;
    float c = 0.0f;
    if (i < N) {
        float qx = p0[3*i]   + fw[3*i];
        float qy = p0[3*i+1] + fw[3*i+1];
        float qz = p0[3*i+2] + fw[3*i+2];
        if (z) { qx -= bwv[3*i]; qy -= bwv[3*i+1]; qz -= bwv[3*i+2]; }
        float q2 = qx*qx + qy*qy + qz*qz;
        float mv = -3.0e38f;
        #pragma unroll
        for (int s = 0; s < NSEG; ++s) mv = fmaxf(mv, part[(size_t)s * N + i]);
        float d2 = fmaf(-2.0f, mv, q2);        // ||q||^2 - 2*max = min sq dist
        d2 = fmaxf(d2, 0.0f);
        c = fminf(d2, TRUNC_VAL);
    }
    #pragma unroll
    for (int off = 32; off > 0; off >>= 1) c += __shfl_down(c, off, 64);
    __shared__ float wsum[256 / 64];
    int lane = threadIdx.x & 63, wid = threadIdx.x >> 6;
    if (lane == 0) wsum[wid] = c;
    __syncthreads();
    if (threadIdx.x == 0) {
        float s = 0.0f;
        #pragma unroll
        for (int w = 0; w < 256 / 64; ++w) s += wsum[w];
        atomicAdd(out, s * inv);
    }
}

extern "C" void kernel_launch(void* const* d_in, const int* in_sizes, int n_in,
                              void* d_out, int out_size, void* d_ws, size_t ws_size,
                              hipStream_t stream) {
    const float* fw  = (const float*)d_in[0];  // fw_flow_pred [N,3]
    const float* bwv = (const float*)d_in[1];  // bw_flow_pred [N,3]
    const float* p0  = (const float*)d_in[2];  // pcl_0 [N,3]
    const float* p1  = (const float*)d_in[3];  // pcl_1 [M,3]
    int N = in_sizes[0] / 3;                   // 16384; M == N for this problem
    int ncol = N / (32 * BPT);                 // 128 query columns

    float* out = (float*)d_out;
    char* w = (char*)d_ws;
    float* Pfw = (float*)w;                    w += (size_t)NSEG * N * 4;
    float* Pbw = (float*)w;

    dim3 grid(ncol / WPB, NSEG, 2);            // (32, 32, 2) = 2048 blocks
    chamfer_mfma_kernel<<<grid, 64 * WPB, 0, stream>>>(
        fw, bwv, p0, p1, Pfw, Pbw, out, N);

    dim3 rgrid((N + 255) / 256, 1, 2);
    reduce_kernel<<<rgrid, 256, 0, stream>>>(
        fw, bwv, p0, Pfw, Pbw, out, N, 1.0f / N);
}

// Round 16
// 26.985 us; speedup vs baseline: 3.7900x; 1.0637x over previous
//
#include <hip/hip_runtime.h>

typedef _Float16 f16x8 __attribute__((ext_vector_type(8)));
typedef float f32x16 __attribute__((ext_vector_type(16)));

#define TRUNC_VAL 2.0f
#define TPS 32     // A-tiles per segment (LDS-resident); NSEG = NT/TPS
#define NSEG 16    // segments for N=16384
#define WPB 4      // waves per block
#define BPT 4      // query (B) tiles per wave: 4 MFMAs per A-frag read

// ---------------------------------------------------------------------------
// R16 = R8/R15 champion (28.6-28.7us, absmax 0.0) with TPS 16 -> 32:
// halves block count (1024), amortizes the B-build prologue + barrier over
// 2x the MFMA work, halves P stripes (16) and reduce's per-query loads.
// Main loop, ILP-4 rhythm, (256,2) bound, and all per-pair math unchanged.
// fmax is exactly associative -> bit-identical P maxima -> absmax 0.0.
// Ledger of nulls/negatives: launch count (R3/R4), zero-remat (R7), (256,1)
// AGPR schedule (R6, -23%), 4-wave/ILP-2 (R9), device fences (R2, -3x),
// spatial pruning family (R10-R14, best 51us — tail-bound).
//
// Fragment layout (verified, absmax 0.0):
//   v_mfma_f32_32x32x16_f16, lane l of tile t at frag[t*64+l],
//   row/col = l&31, k = 8*(l>>5)+i.  hi/lo fp16 split, ~22-bit precision:
//   A (target j): [xh yh zh | xh yh zh | xl yl zl | wh wl | 0...] w=-0.5||y||^2
//   B (query  i): [xh yh zh | xl yl zl | xh yh zh | 1  1  | 0...]
//   => dot = q.y - 0.5||y||^2
// ---------------------------------------------------------------------------
__global__ __launch_bounds__(64 * WPB, 2) void chamfer_mfma_kernel(
    const float* __restrict__ fw, const float* __restrict__ bwv,
    const float* __restrict__ p0, const float* __restrict__ p1,
    float* __restrict__ Pfw, float* __restrict__ Pbw,
    float* __restrict__ out, int N) {
    __shared__ f16x8 Alds[TPS * 64];           // 32 KB: the block's A segment

    int lane = threadIdx.x & 63;
    int wave = threadIdx.x >> 6;
    int r    = lane & 31;
    bool hi  = lane >= 32;
    int col  = blockIdx.x * WPB + wave;        // query column: 128 queries/wave
    int seg  = blockIdx.y;                     // target segment (block-shared)
    int z    = blockIdx.z;
    float* __restrict__ P = z ? Pbw : Pfw;

    // out[0] = 0 once per launch; stream-ordered before reduce's atomicAdds.
    if (threadIdx.x == 0 && blockIdx.x == 0 && blockIdx.y == 0 && z == 0)
        out[0] = 0.0f;

    // ---- build B fragments in registers (once per wave) ----
    f16x8 b[BPT];
    #pragma unroll
    for (int c = 0; c < BPT; ++c) {
        int i = (col * BPT + c) * 32 + r;
        float qx = p0[3*i]   + fw[3*i];
        float qy = p0[3*i+1] + fw[3*i+1];
        float qz = p0[3*i+2] + fw[3*i+2];
        if (z) { qx -= bwv[3*i]; qy -= bwv[3*i+1]; qz -= bwv[3*i+2]; }
        _Float16 xh = (_Float16)qx, yh = (_Float16)qy, zh = (_Float16)qz;
        _Float16 xl = (_Float16)(qx - (float)xh);
        _Float16 yl = (_Float16)(qy - (float)yh);
        _Float16 zl = (_Float16)(qz - (float)zh);
        f16x8 o;
        if (!hi) { o[0]=xh; o[1]=yh; o[2]=zh; o[3]=xl; o[4]=yl; o[5]=zl; o[6]=xh; o[7]=yh; }
        else {
            o[0]=zh; o[1]=(_Float16)1.0f; o[2]=(_Float16)1.0f;
            o[3]=(_Float16)0.0f; o[4]=(_Float16)0.0f; o[5]=(_Float16)0.0f;
            o[6]=(_Float16)0.0f; o[7]=(_Float16)0.0f;
        }
        b[c] = o;
    }

    // ---- build A fragments into LDS (each wave packs TPS/WPB = 8 tiles) ----
    const float* __restrict__ tgt = z ? p0 : p1;
    #pragma unroll
    for (int lt = 0; lt < TPS / WPB; ++lt) {
        int t = wave * (TPS / WPB) + lt;
        int j = (seg * TPS + t) * 32 + r;
        float x = tgt[3*j], y = tgt[3*j+1], zc = tgt[3*j+2];
        _Float16 xh = (_Float16)x, yh = (_Float16)y, zh = (_Float16)zc;
        _Float16 xl = (_Float16)(x  - (float)xh);
        _Float16 yl = (_Float16)(y  - (float)yh);
        _Float16 zl = (_Float16)(zc - (float)zh);
        float w = -0.5f * (x*x + y*y + zc*zc);
        _Float16 wh = (_Float16)w, wl = (_Float16)(w - (float)wh);
        f16x8 o;
        if (!hi) { o[0]=xh; o[1]=yh; o[2]=zh; o[3]=xh; o[4]=yh; o[5]=zh; o[6]=xl; o[7]=yl; }
        else {
            o[0]=zl; o[1]=wh; o[2]=wl;
            o[3]=(_Float16)0.0f; o[4]=(_Float16)0.0f; o[5]=(_Float16)0.0f;
            o[6]=(_Float16)0.0f; o[7]=(_Float16)0.0f;
        }
        Alds[t * 64 + lane] = o;
    }
    __syncthreads();

    // ---- MFMA loop: 4 independent MFMAs in flight, then fold ----
    float m[BPT][4];
    #pragma unroll
    for (int c = 0; c < BPT; ++c)
        #pragma unroll
        for (int p = 0; p < 4; ++p) m[c][p] = -3.0e38f;

    const f32x16 zero = {};
    f16x8 a = Alds[lane];

#define FOLD(c, d)                                                  \
    _Pragma("unroll")                                               \
    for (int p = 0; p < 4; ++p) {                                   \
        m[c][p] = fmaxf(fmaxf(m[c][p], d[4*p  ]), d[4*p+1]);        \
        m[c][p] = fmaxf(fmaxf(m[c][p], d[4*p+2]), d[4*p+3]);        \
    }

    for (int t = 0; t < TPS; ++t) {
        f16x8 a_cur = a;
        int tn = (t + 1 < TPS) ? t + 1 : t;
        a = Alds[tn * 64 + lane];              // prefetch next A-frag
        f32x16 d0 = __builtin_amdgcn_mfma_f32_32x32x16_f16(a_cur, b[0], zero, 0, 0, 0);
        f32x16 d1 = __builtin_amdgcn_mfma_f32_32x32x16_f16(a_cur, b[1], zero, 0, 0, 0);
        f32x16 d2 = __builtin_amdgcn_mfma_f32_32x32x16_f16(a_cur, b[2], zero, 0, 0, 0);
        f32x16 d3 = __builtin_amdgcn_mfma_f32_32x32x16_f16(a_cur, b[3], zero, 0, 0, 0);
        FOLD(0, d0) FOLD(1, d1) FOLD(2, d2) FOLD(3, d3)
    }
#undef FOLD

    #pragma unroll
    for (int c = 0; c < BPT; ++c) {
        float v = fmaxf(fmaxf(m[c][0], m[c][1]), fmaxf(m[c][2], m[c][3]));
        v = fmaxf(v, __shfl_xor(v, 32, 64));   // fold the two row-halves
        if (lane < 32) P[(size_t)seg * N + col * (32 * BPT) + c * 32 + lane] = v;
    }
}

// ---------------------------------------------------------------------------
// Combine segment maxima, form truncated chamfer per query, mean-reduce.
// ---------------------------------------------------------------------------
__global__ __launch_bounds__(256) void reduce_kernel(
    const float* __restrict__ fw, const float* __restrict__ bwv,
    const float* __restrict__ p0,
    const float* __restrict__ Pfw, const float* __restrict__ Pbw,
    float* __restrict__ out, int N, float inv) {
    int z = blockIdx.z;
    const float* __restrict__ part = z ? Pbw : Pfw;

    int i = blockIdx.x * blockDim.x + threadIdx.x;
    float c = 0.0f;
    if (i < N) {
        float qx = p0[3*i]   + fw[3*i];
        float qy = p0[3*i+1] + fw[3*i+1];
        float qz = p0[3*i+2] + fw[3*i+2];
        if (z) { qx -= bwv[3*i]; qy -= bwv[3*i+1]; qz -= bwv[3*i+2]; }
        float q2 = qx*qx + qy*qy + qz*qz;
        float mv = -3.0e38f;
        #pragma unroll
        for (int s = 0; s < NSEG; ++s) mv = fmaxf(mv, part[(size_t)s * N + i]);
        float d2 = fmaf(-2.0f, mv, q2);        // ||q||^2 - 2*max = min sq dist
        d2 = fmaxf(d2, 0.0f);
        c = fminf(d2, TRUNC_VAL);
    }
    #pragma unroll
    for (int off = 32; off > 0; off >>= 1) c += __shfl_down(c, off, 64);
    __shared__ float wsum[256 / 64];
    int lane = threadIdx.x & 63, wid = threadIdx.x >> 6;
    if (lane == 0) wsum[wid] = c;
    __syncthreads();
    if (threadIdx.x == 0) {
        float s = 0.0f;
        #pragma unroll
        for (int w = 0; w < 256 / 64; ++w) s += wsum[w];
        atomicAdd(out, s * inv);
    }
}

extern "C" void kernel_launch(void* const* d_in, const int* in_sizes, int n_in,
                              void* d_out, int out_size, void* d_ws, size_t ws_size,
                              hipStream_t stream) {
    const float* fw  = (const float*)d_in[0];  // fw_flow_pred [N,3]
    const float* bwv = (const float*)d_in[1];  // bw_flow_pred [N,3]
    const float* p0  = (const float*)d_in[2];  // pcl_0 [N,3]
    const float* p1  = (const float*)d_in[3];  // pcl_1 [M,3]
    int N = in_sizes[0] / 3;                   // 16384; M == N for this problem
    int ncol = N / (32 * BPT);                 // 128 query columns

    float* out = (float*)d_out;
    char* w = (char*)d_ws;
    float* Pfw = (float*)w;                    w += (size_t)NSEG * N * 4;
    float* Pbw = (float*)w;

    dim3 grid(ncol / WPB, NSEG, 2);            // (32, 16, 2) = 1024 blocks
    chamfer_mfma_kernel<<<grid, 64 * WPB, 0, stream>>>(
        fw, bwv, p0, p1, Pfw, Pbw, out, N);

    dim3 rgrid((N + 255) / 256, 1, 2);
    reduce_kernel<<<rgrid, 256, 0, stream>>>(
        fw, bwv, p0, Pfw, Pbw, out, N, 1.0f / N);
}